// Round 4
// baseline (242.852 us; speedup 1.0000x reference)
//
#include <hip/hip_runtime.h>

#define HW 28
#define NPIX 784
#define NB 512
#define PADW2 36                 // padded row stride in float2 (16B-aligned rows)
#define PADH 34                  // rows -3..30
#define IMG_F2 (PADH * PADW2)    // 1224 float2 = 9792 B per image

typedef float v2f __attribute__((ext_vector_type(2)));

// ---------------------------------------------------------------------------
// wtab[f*2+s][t] = (ew, qw) = (exp(a*w), w*exp(a*w))
// ---------------------------------------------------------------------------
__global__ void setup_wtab(const float* __restrict__ w,
                           const float* __restrict__ alpha,
                           float2* __restrict__ wtab)
{
    int idx = blockIdx.x * 256 + threadIdx.x;
    if (idx < 16 * 49) {
        int fs = idx / 49;
        int t  = idx - fs * 49;
        float a  = alpha[fs];
        float wv = w[fs * 49 + t];
        float e  = __expf(a * wv);
        wtab[idx] = make_float2(e, wv * e);
    }
}

// ---------------------------------------------------------------------------
// 7x2 output tile per thread. Taps: 13 rows x 4 ds_read_b128 (8 float2/row).
// Per tap-output: 1 v_pk_fma_f32 (sD,sA) + 1 scalar fma (sB).
// out = (sum pv*ew + sum ev*qw) / (sum ev*ew)
// ---------------------------------------------------------------------------
__device__ __forceinline__ void conv2col(const float2* sbuf,
                                         const float2* __restrict__ wt,  // uniform
                                         int R0, int c, float o0[7], float o1[7])
{
    v2f sDA0[7], sDA1[7];
    float sB0[7], sB1[7];
#pragma unroll
    for (int r = 0; r < 7; ++r) {
        sDA0[r] = (v2f){0.f, 0.f}; sDA1[r] = (v2f){0.f, 0.f};
        sB0[r] = 0.f; sB1[r] = 0.f;
    }
#pragma unroll
    for (int rr = 0; rr < 13; ++rr) {
        const float4* rowq = (const float4*)(sbuf + (R0 + rr) * PADW2) + c * 2;
        float4 q0 = rowq[0], q1 = rowq[1], q2 = rowq[2], q3 = rowq[3];
        v2f tap[8];
        tap[0] = (v2f){q0.x, q0.y}; tap[1] = (v2f){q0.z, q0.w};
        tap[2] = (v2f){q1.x, q1.y}; tap[3] = (v2f){q1.z, q1.w};
        tap[4] = (v2f){q2.x, q2.y}; tap[5] = (v2f){q2.z, q2.w};
        tap[6] = (v2f){q3.x, q3.y}; tap[7] = (v2f){q3.z, q3.w};
#pragma unroll
        for (int r = 0; r < 7; ++r) {
            if (r > rr || rr - r > 6) continue;     // compile-time fold
            const float2* wrow = wt + (rr - r) * 7;
#pragma unroll
            for (int t = 0; t < 7; ++t) {
                float2 wv = wrow[t];
                v2f ew2 = {wv.x, wv.x};
                sDA0[r] = __builtin_elementwise_fma(tap[t],     ew2, sDA0[r]);
                sDA1[r] = __builtin_elementwise_fma(tap[t + 1], ew2, sDA1[r]);
                sB0[r] = fmaf(tap[t][0],     wv.y, sB0[r]);
                sB1[r] = fmaf(tap[t + 1][0], wv.y, sB1[r]);
            }
        }
    }
#pragma unroll
    for (int r = 0; r < 7; ++r) {
        o0[r] = (sDA0[r][1] + sB0[r]) * __builtin_amdgcn_rcpf(sDA0[r][0]);
        o1[r] = (sDA1[r][1] + sB1[r]) * __builtin_amdgcn_rcpf(sDA1[r][0]);
    }
}

// ---------------------------------------------------------------------------
// Fused smorph x2 + 4x4 mean pool. 128 threads = 2 image-pure waves.
// Single evpv buffer per image, reused across both stages (19.6 KB/block ->
// 8 blocks/CU). Thread = 7 rows x 2 cols tile (56 active lanes per wave).
// ---------------------------------------------------------------------------
__global__ __launch_bounds__(128, 4) void smorph_fused_kernel(
    const float* __restrict__ x,       // [512,784]
    const float2* __restrict__ wtab,   // [16,49]
    const float* __restrict__ alpha,   // [8,2]
    float* __restrict__ feat)          // [512,392]
{
    __shared__ __align__(16) float2 evpv[2][IMG_F2];

    const int bx   = blockIdx.x;       // 2048 blocks
    const int f    = bx >> 8;
    const int bp   = bx & 255;
    const int tid  = threadIdx.x;
    const int img  = tid >> 6;         // wave-pure image assignment
    const int lane = tid & 63;
    const int b    = bp * 2 + img;

    const float a1 = alpha[f * 2 + 0];
    const float a2 = alpha[f * 2 + 1];
    const float2* wt1 = wtab + (f * 2 + 0) * 49;
    const float2* wt2 = wtab + (f * 2 + 1) * 49;

    float2* buf = evpv[img];

    // Phase 0: init padded (ev,pv) for stage 1; borders = (1,0) (SAME zero-pad)
    const float* src = x + (size_t)b * NPIX;
    for (int idx = lane; idx < IMG_F2; idx += 64) {
        int pi = idx / PADW2;
        int pj = idx - pi * PADW2;
        float2 val = make_float2(1.f, 0.f);
        if (pi >= 3 && pi < 31 && pj >= 3 && pj < 31) {
            float v = src[(pi - 3) * HW + (pj - 3)];
            float e = __expf(a1 * v);
            val = make_float2(e, v * e);
        }
        buf[idx] = val;
    }
    __syncthreads();

    const bool act = (lane < 56);
    const int s  = lane / 14;          // strip 0..3 (rows 7s..7s+6)
    const int c  = lane - s * 14;      // column pair 0..13
    const int R0 = 7 * s;
    const int j2 = 2 * c;

    float o0[7], o1[7];
    if (act) conv2col(buf, wt1, R0, c, o0, o1);
    __syncthreads();                   // all stage-1 reads complete

    // Phase 2: overwrite interior with stage-2 (ev,pv); borders remain (1,0)
    if (act) {
#pragma unroll
        for (int r = 0; r < 7; ++r) {
            float e0 = __expf(a2 * o0[r]);
            float e1 = __expf(a2 * o1[r]);
            buf[(R0 + r + 3) * PADW2 + (j2 + 3)] = make_float2(e0, o0[r] * e0);
            buf[(R0 + r + 3) * PADW2 + (j2 + 4)] = make_float2(e1, o1[r] * e1);
        }
    }
    __syncthreads();

    if (act) conv2col(buf, wt2, R0, c, o0, o1);
    __syncthreads();                   // all stage-2 reads complete

    // Phase 4: write stage-2 outputs as a dense 28x28 float plane (alias buf)
    float* outp = (float*)buf;
    if (act) {
#pragma unroll
        for (int r = 0; r < 7; ++r) {
            outp[(R0 + r) * HW + j2]     = o0[r];
            outp[(R0 + r) * HW + j2 + 1] = o1[r];
        }
    }
    __syncthreads();

    // Phase 5: 4x4 mean pool -> feat[b, f*49 + t]
    if (lane < 49) {
        int pi = lane / 7;
        int pj = lane - pi * 7;
        float sum = 0.f;
#pragma unroll
        for (int di = 0; di < 4; ++di)
#pragma unroll
            for (int dj = 0; dj < 4; ++dj)
                sum += outp[(pi * 4 + di) * HW + (pj * 4 + dj)];
        feat[(size_t)b * 392 + f * 49 + lane] = sum * 0.0625f;
    }
}

// ---------------------------------------------------------------------------
// MLP 392->120->84->10, sigmoid. One block per batch row; dots split across
// lanes with component-parallel accumulators + shuffle reduce.
// ---------------------------------------------------------------------------
__device__ __forceinline__ float sigmoidf_(float s) {
    return __builtin_amdgcn_rcpf(1.f + __expf(-s));
}

__global__ __launch_bounds__(256) void mlp_kernel(
    const float* __restrict__ feat,
    const float* __restrict__ W1, const float* __restrict__ b1,
    const float* __restrict__ W2, const float* __restrict__ b2,
    const float* __restrict__ W3, const float* __restrict__ b3,
    float* __restrict__ out)
{
    __shared__ __align__(16) float fsh[392];
    __shared__ __align__(16) float h1[120];
    __shared__ __align__(16) float h2[84];
    const int b   = blockIdx.x;
    const int tid = threadIdx.x;

    if (tid < 98)
        ((float4*)fsh)[tid] = ((const float4*)(feat + (size_t)b * 392))[tid];
    __syncthreads();

    if (tid < 240) {
        int n = tid >> 1, h = tid & 1;
        const float4* wr = (const float4*)(W1 + n * 392);
        const float4* fv = (const float4*)fsh;
        float c0 = 0.f, c1 = 0.f, c2 = 0.f, c3 = 0.f;
#pragma unroll 7
        for (int k = h; k < 98; k += 2) {
            float4 w = wr[k];
            float4 v = fv[k];
            c0 = fmaf(w.x, v.x, c0);
            c1 = fmaf(w.y, v.y, c1);
            c2 = fmaf(w.z, v.z, c2);
            c3 = fmaf(w.w, v.w, c3);
        }
        float acc = (c0 + c1) + (c2 + c3);
        acc += __shfl_xor(acc, 1);
        if (h == 0) h1[n] = sigmoidf_(acc + b1[n]);
    }
    __syncthreads();

    if (tid < 168) {
        int n = tid >> 1, h = tid & 1;
        const float4* wr = (const float4*)(W2 + n * 120);
        const float4* hv = (const float4*)h1;
        float c0 = 0.f, c1 = 0.f, c2 = 0.f, c3 = 0.f;
#pragma unroll
        for (int k = h; k < 30; k += 2) {
            float4 w = wr[k];
            float4 v = hv[k];
            c0 = fmaf(w.x, v.x, c0);
            c1 = fmaf(w.y, v.y, c1);
            c2 = fmaf(w.z, v.z, c2);
            c3 = fmaf(w.w, v.w, c3);
        }
        float acc = (c0 + c1) + (c2 + c3);
        acc += __shfl_xor(acc, 1);
        if (h == 0) h2[n] = sigmoidf_(acc + b2[n]);
    }
    __syncthreads();

    if (tid < 40) {
        int n = tid >> 2, q = tid & 3;
        const float4* wr = (const float4*)(W3 + n * 84);
        const float4* hv = (const float4*)h2;
        float c0 = 0.f, c1 = 0.f, c2 = 0.f, c3 = 0.f;
        for (int k = q; k < 21; k += 4) {
            float4 w = wr[k];
            float4 v = hv[k];
            c0 = fmaf(w.x, v.x, c0);
            c1 = fmaf(w.y, v.y, c1);
            c2 = fmaf(w.z, v.z, c2);
            c3 = fmaf(w.w, v.w, c3);
        }
        float acc = (c0 + c1) + (c2 + c3);
        acc += __shfl_xor(acc, 1);
        acc += __shfl_xor(acc, 2);
        if (q == 0) out[(size_t)b * 10 + n] = sigmoidf_(acc + b3[n]);
    }
}

extern "C" void kernel_launch(void* const* d_in, const int* in_sizes, int n_in,
                              void* d_out, int out_size, void* d_ws, size_t ws_size,
                              hipStream_t stream) {
    const float* x  = (const float*)d_in[0];
    const float* sw = (const float*)d_in[1];
    const float* sa = (const float*)d_in[2];
    const float* W1 = (const float*)d_in[3];
    const float* b1 = (const float*)d_in[4];
    const float* W2 = (const float*)d_in[5];
    const float* b2 = (const float*)d_in[6];
    const float* W3 = (const float*)d_in[7];
    const float* b3 = (const float*)d_in[8];
    float* out = (float*)d_out;

    float2* wtab = (float2*)d_ws;                  // 16*49 float2 = 6272 B
    float*  feat = (float*)d_ws + 2 * 16 * 49;     // 512*392 floats

    setup_wtab<<<4, 256, 0, stream>>>(sw, sa, wtab);
    smorph_fused_kernel<<<2048, 128, 0, stream>>>(x, wtab, sa, feat);
    mlp_kernel<<<NB, 256, 0, stream>>>(feat, W1, b1, W2, b2, W3, b3, out);
}

// Round 5
// 127.781 us; speedup vs baseline: 1.9005x; 1.9005x over previous
//
#include <hip/hip_runtime.h>

#define HW 28
#define NPIX 784
#define NB 512
#define PADW2 34                 // row stride in float2 (cols -3..30), 272 B
#define PADH 34                  // rows -3..30
#define IMG_F2 (PADH * PADW2)    // 1156 float2 = 9248 B per image

typedef float v2f __attribute__((ext_vector_type(2)));

// ---------------------------------------------------------------------------
// wtab[fs][t] = (qw, ew) = (w*exp(a*w), exp(a*w))   -- qw FIRST, so that
// (ev,pv) . (qw,ew) = (ev*qw, pv*ew) is the numerator pair via one pk_fma.
// ---------------------------------------------------------------------------
__global__ void setup_wtab(const float* __restrict__ w,
                           const float* __restrict__ alpha,
                           float2* __restrict__ wtab)
{
    int idx = blockIdx.x * 256 + threadIdx.x;
    if (idx < 16 * 49) {
        int fs = idx / 49;
        int t  = idx - fs * 49;
        float a  = alpha[fs];
        float wv = w[fs * 49 + t];
        float e  = __expf(a * wv);
        wtab[idx] = make_float2(wv * e, e);
    }
}

// ---------------------------------------------------------------------------
// 7x2 output tile per thread. Per row: 4 ds_read_b128 (8 float2 taps).
// Per tap per output: 1 v_pk_fma_f32 (numerator pair) + 1 v_fma (denominator).
// out = (ev.qw + pv.ew summed) / (ev.ew summed)
// ---------------------------------------------------------------------------
__device__ __forceinline__ void conv2col(const float2* sbuf,
                                         const float2* __restrict__ wt,  // uniform (SGPR)
                                         int R0, int c, float o0[7], float o1[7])
{
    v2f   sN0[7], sN1[7];
    float sD0[7], sD1[7];
#pragma unroll
    for (int r = 0; r < 7; ++r) {
        sN0[r] = (v2f){0.f, 0.f}; sN1[r] = (v2f){0.f, 0.f};
        sD0[r] = 0.f; sD1[r] = 0.f;
    }
#pragma unroll
    for (int rr = 0; rr < 13; ++rr) {
        const float4* rq = (const float4*)(sbuf + (R0 + rr) * PADW2 + 2 * c);
        float4 q0 = rq[0], q1 = rq[1], q2 = rq[2], q3 = rq[3];
        v2f tp[8];
        tp[0] = (v2f){q0.x, q0.y}; tp[1] = (v2f){q0.z, q0.w};
        tp[2] = (v2f){q1.x, q1.y}; tp[3] = (v2f){q1.z, q1.w};
        tp[4] = (v2f){q2.x, q2.y}; tp[5] = (v2f){q2.z, q2.w};
        tp[6] = (v2f){q3.x, q3.y}; tp[7] = (v2f){q3.z, q3.w};
#pragma unroll
        for (int r = 0; r < 7; ++r) {
            if (r > rr || rr - r > 6) continue;     // compile-time fold
            const float2* wrow = wt + (rr - r) * 7;
#pragma unroll
            for (int t = 0; t < 7; ++t) {
                float2 wv = wrow[t];                // (qw, ew) in SGPRs
                v2f wq = {wv.x, wv.y};
                sN0[r] = __builtin_elementwise_fma(tp[t],     wq, sN0[r]);
                sN1[r] = __builtin_elementwise_fma(tp[t + 1], wq, sN1[r]);
                sD0[r] = fmaf(tp[t][0],     wv.y, sD0[r]);
                sD1[r] = fmaf(tp[t + 1][0], wv.y, sD1[r]);
            }
        }
    }
#pragma unroll
    for (int r = 0; r < 7; ++r) {
        o0[r] = (sN0[r][0] + sN0[r][1]) * __builtin_amdgcn_rcpf(sD0[r]);
        o1[r] = (sN1[r][0] + sN1[r][1]) * __builtin_amdgcn_rcpf(sD1[r]);
    }
}

// ---------------------------------------------------------------------------
// Fused smorph x2 + 4x4 mean pool. 256 threads = 4 image-pure waves, one
// image per wave, single in-place evpv buffer per image (37 KB/block ->
// 4 blocks/CU). Thread tile: 7 rows x 2 cols (56 active lanes per wave).
// __launch_bounds__(256,2): VGPR cap 256 so the ~70-reg live set does NOT
// spill (round-4 lesson: spills at cap 64 cost 525 MB of scratch traffic).
// ---------------------------------------------------------------------------
__global__ __launch_bounds__(256, 2) void smorph_fused_kernel(
    const float* __restrict__ x,       // [512,784]
    const float2* __restrict__ wtab,   // [16,49] (qw,ew)
    const float* __restrict__ alpha,   // [8,2]
    float* __restrict__ feat)          // [512,392]
{
    __shared__ __align__(16) float2 evpv[4][IMG_F2];   // 36,992 B

    const int bx   = blockIdx.x;       // 1024 blocks = 8 f x 128 quads
    const int f    = bx >> 7;
    const int bq   = bx & 127;
    const int tid  = threadIdx.x;
    const int wv   = tid >> 6;         // wave -> image
    const int lane = tid & 63;
    const int b    = bq * 4 + wv;

    const float a1 = alpha[f * 2 + 0];
    const float a2 = alpha[f * 2 + 1];
    const float2* wt1 = wtab + (f * 2 + 0) * 49;
    const float2* wt2 = wtab + (f * 2 + 1) * 49;

    float2* buf = evpv[wv];

    // Phase 0: padded (ev,pv) for stage 1; borders (1,0)  (SAME zero-pad)
    const float* src = x + (size_t)b * NPIX;
    for (int idx = lane; idx < IMG_F2; idx += 64) {
        int pi = idx / PADW2;
        int pj = idx - pi * PADW2;
        float2 val = make_float2(1.f, 0.f);
        if (pi >= 3 && pi < 31 && pj >= 3 && pj < 31) {
            float v = src[(pi - 3) * HW + (pj - 3)];
            float e = __expf(a1 * v);
            val = make_float2(e, v * e);
        }
        buf[idx] = val;
    }
    __syncthreads();

    const bool act = (lane < 56);
    const int s  = lane / 14;          // strip 0..3 (output rows 7s..7s+6)
    const int c  = lane - s * 14;      // column pair 0..13
    const int R0 = 7 * s;
    const int j2 = 2 * c;

    float o0[7], o1[7];
    if (act) conv2col(buf, wt1, R0, c, o0, o1);
    __syncthreads();                   // all stage-1 reads complete

    // Phase 2: overwrite interior with stage-2 (ev,pv); borders stay (1,0)
    if (act) {
#pragma unroll
        for (int r = 0; r < 7; ++r) {
            float e0 = __expf(a2 * o0[r]);
            float e1 = __expf(a2 * o1[r]);
            buf[(R0 + r + 3) * PADW2 + (j2 + 3)] = make_float2(e0, o0[r] * e0);
            buf[(R0 + r + 3) * PADW2 + (j2 + 4)] = make_float2(e1, o1[r] * e1);
        }
    }
    __syncthreads();

    if (act) conv2col(buf, wt2, R0, c, o0, o1);
    __syncthreads();                   // all stage-2 reads complete

    // Phase 4: dense 28x28 float plane (aliases buf; reads are done)
    float* outp = (float*)buf;
    if (act) {
#pragma unroll
        for (int r = 0; r < 7; ++r) {
            outp[(R0 + r) * HW + j2]     = o0[r];
            outp[(R0 + r) * HW + j2 + 1] = o1[r];
        }
    }
    __syncthreads();

    // Phase 5: 4x4 mean pool -> feat[b, f*49 + t]
    if (lane < 49) {
        int pi = lane / 7;
        int pj = lane - pi * 7;
        float sum = 0.f;
#pragma unroll
        for (int di = 0; di < 4; ++di)
#pragma unroll
            for (int dj = 0; dj < 4; ++dj)
                sum += outp[(pi * 4 + di) * HW + (pj * 4 + dj)];
        feat[(size_t)b * 392 + f * 49 + lane] = sum * 0.0625f;
    }
}

// ---------------------------------------------------------------------------
// MLP 392->120->84->10, sigmoid. One block per batch row; dots split across
// lanes with component-parallel accumulators + shuffle reduce.
// ---------------------------------------------------------------------------
__device__ __forceinline__ float sigmoidf_(float s) {
    return __builtin_amdgcn_rcpf(1.f + __expf(-s));
}

__global__ __launch_bounds__(256) void mlp_kernel(
    const float* __restrict__ feat,
    const float* __restrict__ W1, const float* __restrict__ b1,
    const float* __restrict__ W2, const float* __restrict__ b2,
    const float* __restrict__ W3, const float* __restrict__ b3,
    float* __restrict__ out)
{
    __shared__ __align__(16) float fsh[392];
    __shared__ __align__(16) float h1[120];
    __shared__ __align__(16) float h2[84];
    const int b   = blockIdx.x;
    const int tid = threadIdx.x;

    if (tid < 98)
        ((float4*)fsh)[tid] = ((const float4*)(feat + (size_t)b * 392))[tid];
    __syncthreads();

    if (tid < 240) {
        int n = tid >> 1, h = tid & 1;
        const float4* wr = (const float4*)(W1 + n * 392);
        const float4* fv = (const float4*)fsh;
        float c0 = 0.f, c1 = 0.f, c2 = 0.f, c3 = 0.f;
#pragma unroll 7
        for (int k = h; k < 98; k += 2) {
            float4 w = wr[k];
            float4 v = fv[k];
            c0 = fmaf(w.x, v.x, c0);
            c1 = fmaf(w.y, v.y, c1);
            c2 = fmaf(w.z, v.z, c2);
            c3 = fmaf(w.w, v.w, c3);
        }
        float acc = (c0 + c1) + (c2 + c3);
        acc += __shfl_xor(acc, 1);
        if (h == 0) h1[n] = sigmoidf_(acc + b1[n]);
    }
    __syncthreads();

    if (tid < 168) {
        int n = tid >> 1, h = tid & 1;
        const float4* wr = (const float4*)(W2 + n * 120);
        const float4* hv = (const float4*)h1;
        float c0 = 0.f, c1 = 0.f, c2 = 0.f, c3 = 0.f;
#pragma unroll
        for (int k = h; k < 30; k += 2) {
            float4 w = wr[k];
            float4 v = hv[k];
            c0 = fmaf(w.x, v.x, c0);
            c1 = fmaf(w.y, v.y, c1);
            c2 = fmaf(w.z, v.z, c2);
            c3 = fmaf(w.w, v.w, c3);
        }
        float acc = (c0 + c1) + (c2 + c3);
        acc += __shfl_xor(acc, 1);
        if (h == 0) h2[n] = sigmoidf_(acc + b2[n]);
    }
    __syncthreads();

    if (tid < 40) {
        int n = tid >> 2, q = tid & 3;
        const float4* wr = (const float4*)(W3 + n * 84);
        const float4* hv = (const float4*)h2;
        float c0 = 0.f, c1 = 0.f, c2 = 0.f, c3 = 0.f;
        for (int k = q; k < 21; k += 4) {
            float4 w = wr[k];
            float4 v = hv[k];
            c0 = fmaf(w.x, v.x, c0);
            c1 = fmaf(w.y, v.y, c1);
            c2 = fmaf(w.z, v.z, c2);
            c3 = fmaf(w.w, v.w, c3);
        }
        float acc = (c0 + c1) + (c2 + c3);
        acc += __shfl_xor(acc, 1);
        acc += __shfl_xor(acc, 2);
        if (q == 0) out[(size_t)b * 10 + n] = sigmoidf_(acc + b3[n]);
    }
}

extern "C" void kernel_launch(void* const* d_in, const int* in_sizes, int n_in,
                              void* d_out, int out_size, void* d_ws, size_t ws_size,
                              hipStream_t stream) {
    const float* x  = (const float*)d_in[0];
    const float* sw = (const float*)d_in[1];
    const float* sa = (const float*)d_in[2];
    const float* W1 = (const float*)d_in[3];
    const float* b1 = (const float*)d_in[4];
    const float* W2 = (const float*)d_in[5];
    const float* b2 = (const float*)d_in[6];
    const float* W3 = (const float*)d_in[7];
    const float* b3 = (const float*)d_in[8];
    float* out = (float*)d_out;

    float2* wtab = (float2*)d_ws;                  // 16*49 float2 = 6272 B
    float*  feat = (float*)d_ws + 2 * 16 * 49;     // 512*392 floats

    setup_wtab<<<4, 256, 0, stream>>>(sw, sa, wtab);
    smorph_fused_kernel<<<1024, 256, 0, stream>>>(x, wtab, sa, feat);
    mlp_kernel<<<NB, 256, 0, stream>>>(feat, W1, b1, W2, b2, W3, b3, out);
}